// Round 1
// baseline (291.601 us; speedup 1.0000x reference)
//
#include <hip/hip_runtime.h>

#define S_LEN 4096
#define DMODEL 768
#define NHEADS 12
#define DKH 64

typedef __attribute__((ext_vector_type(8))) short bf16x8;
typedef __attribute__((ext_vector_type(4))) float f32x4;
typedef __attribute__((ext_vector_type(4))) short s16x4;

#define AS1 __attribute__((address_space(1)))
#define AS3 __attribute__((address_space(3)))

__device__ __forceinline__ short f2bf(float f) {
    union { float f; unsigned u; } x; x.f = f;
    unsigned r = x.u + 0x7fffu + ((x.u >> 16) & 1u);
    return (short)(r >> 16);
}

__device__ __forceinline__ void gload_lds16(const void* g, void* l) {
    __builtin_amdgcn_global_load_lds((const AS1 void*)g, (AS3 void*)l, 16, 0, 0);
}

// ---------------- fp32 -> bf16 convert (8 elems/thread) ----------------
__global__ void cvt_bf16(const float* __restrict__ src, short* __restrict__ dst, int n8) {
    int stride = gridDim.x * blockDim.x;
    for (int i = blockIdx.x * blockDim.x + threadIdx.x; i < n8; i += stride) {
        float4 a = ((const float4*)src)[2 * i];
        float4 b = ((const float4*)src)[2 * i + 1];
        bf16x8 o;
        o[0] = f2bf(a.x); o[1] = f2bf(a.y); o[2] = f2bf(a.z); o[3] = f2bf(a.w);
        o[4] = f2bf(b.x); o[5] = f2bf(b.y); o[6] = f2bf(b.z); o[7] = f2bf(b.w);
        ((bf16x8*)dst)[i] = o;
    }
}

// ---------------- mask int32 [S][S] -> bitmask [S][S/64] ----------------
__global__ void pack_mask_k(const int* __restrict__ mask, unsigned long long* __restrict__ mp, int nwords) {
    int lane = threadIdx.x & 63;
    int wid = (blockIdx.x * blockDim.x + threadIdx.x) >> 6;
    int nw = (gridDim.x * blockDim.x) >> 6;
    for (int w = wid; w < nwords; w += nw) {
        int m = mask[(size_t)w * 64 + lane];
        unsigned long long b = __ballot(m != 0);
        if (lane == 0) mp[w] = b;
    }
}

// ---------------- GEMM: C[M=4096][N=768] = A[4096][768] @ B[768][768]^T + bias ----
// EPI 0: bf16 out, per-head layout [h][s][d]   (Q, K projections)
// EPI 1: bf16 out, transposed     [h][d][s]   (V projection)
// EPI 2: fp32 out, [s][o] + bias              (output projection)
template<int EPI>
__global__ __launch_bounds__(256) void gemm_bt(
    const short* __restrict__ A, const short* __restrict__ B,
    const float* __restrict__ bias, void* __restrict__ outp)
{
    __shared__ __align__(16) short As[128 * 64];
    __shared__ __align__(16) short Bs[128 * 64];
    const int tid = threadIdx.x;
    const int wv = tid >> 6, l = tid & 63;
    const int wr = wv >> 1, wc = wv & 1;
    const int g = l >> 4, hl = l & 15;
    const int m0 = blockIdx.x * 128, n0 = blockIdx.y * 128;
    const int Kd = DMODEL;

    f32x4 acc[4][4] = {};

    for (int kt = 0; kt < Kd; kt += 64) {
        __syncthreads();
        #pragma unroll
        for (int i = 0; i < 4; ++i) {
            int row = i * 32 + wv * 8 + (l >> 3);
            int csrc = (l & 7) ^ (row & 7);
            gload_lds16(A + (size_t)(m0 + row) * Kd + kt + csrc * 8, As + (i * 32 + wv * 8) * 64);
        }
        #pragma unroll
        for (int i = 0; i < 4; ++i) {
            int row = i * 32 + wv * 8 + (l >> 3);
            int csrc = (l & 7) ^ (row & 7);
            gload_lds16(B + (size_t)(n0 + row) * Kd + kt + csrc * 8, Bs + (i * 32 + wv * 8) * 64);
        }
        __syncthreads();
        #pragma unroll
        for (int s = 0; s < 2; ++s) {
            bf16x8 af[4], bf[4];
            #pragma unroll
            for (int m = 0; m < 4; ++m) {
                int row = wr * 64 + m * 16 + hl;
                int ch = (s * 4 + g) ^ (row & 7);
                af[m] = *(const bf16x8*)(As + row * 64 + ch * 8);
            }
            #pragma unroll
            for (int n = 0; n < 4; ++n) {
                int row = wc * 64 + n * 16 + hl;
                int ch = (s * 4 + g) ^ (row & 7);
                bf[n] = *(const bf16x8*)(Bs + row * 64 + ch * 8);
            }
            #pragma unroll
            for (int m = 0; m < 4; ++m)
                #pragma unroll
                for (int n = 0; n < 4; ++n)
                    acc[m][n] = __builtin_amdgcn_mfma_f32_16x16x32_bf16(af[m], bf[n], acc[m][n], 0, 0, 0);
        }
    }

    #pragma unroll
    for (int m = 0; m < 4; ++m) {
        #pragma unroll
        for (int n = 0; n < 4; ++n) {
            int gsb = m0 + wr * 64 + m * 16 + g * 4;
            int go = n0 + wc * 64 + n * 16 + hl;
            float bv = bias[go];
            if (EPI == 2) {
                float* O = (float*)outp;
                #pragma unroll
                for (int r = 0; r < 4; ++r)
                    O[(size_t)(gsb + r) * DMODEL + go] = acc[m][n][r] + bv;
            } else if (EPI == 0) {
                short* O = (short*)outp;
                int h = go >> 6, d = go & 63;
                #pragma unroll
                for (int r = 0; r < 4; ++r)
                    O[(size_t)h * S_LEN * DKH + (size_t)(gsb + r) * DKH + d] = f2bf(acc[m][n][r] + bv);
            } else {
                short* O = (short*)outp;
                int h = go >> 6, d = go & 63;
                s16x4 p;
                #pragma unroll
                for (int r = 0; r < 4; ++r) p[r] = f2bf(acc[m][n][r] + bv);
                *(s16x4*)(O + (size_t)h * DKH * S_LEN + (size_t)d * S_LEN + gsb) = p;
            }
        }
    }
}

// ---------------- flash attention, one head x 64 q-rows per block --------------
// Qh/Kh: [12][4096][64] bf16 ; Vt: [12][64][4096] bf16 ; mp: [4096][64] u64
// ctx out: [4096][768] bf16 (head-concat)
__global__ __launch_bounds__(256) void flash_attn(
    const short* __restrict__ Qh, const short* __restrict__ Kh,
    const short* __restrict__ Vt, const unsigned long long* __restrict__ mp,
    short* __restrict__ ctx)
{
    __shared__ __align__(16) short Ks[64 * 64];
    __shared__ __align__(16) short Vs[64 * 64];
    __shared__ __align__(16) short Ps[4][1024];

    const int tid = threadIdx.x;
    const int wv = tid >> 6, l = tid & 63;
    const int g = l >> 4, hl = l & 15;
    const int h = blockIdx.y;
    const int q0 = blockIdx.x * 64;
    const int qr = q0 + wv * 16;

    bf16x8 aq[2];
    #pragma unroll
    for (int s = 0; s < 2; ++s)
        aq[s] = *(const bf16x8*)(Qh + (size_t)h * S_LEN * DKH + (size_t)(qr + hl) * DKH + s * 32 + g * 8);

    float mrun[4], drun[4];
    f32x4 acco[4] = {};
    #pragma unroll
    for (int r = 0; r < 4; ++r) { mrun[r] = -3.0e38f; drun[r] = 0.f; }

    for (int kt = 0; kt < S_LEN / 64; ++kt) {
        const int kv0 = kt * 64;
        __syncthreads();
        #pragma unroll
        for (int i = 0; i < 2; ++i) {
            int row = i * 32 + wv * 8 + (l >> 3);
            int csrc = (l & 7) ^ (row & 7);
            gload_lds16(Kh + (size_t)h * S_LEN * DKH + (size_t)(kv0 + row) * DKH + csrc * 8,
                        Ks + (i * 32 + wv * 8) * 64);
            gload_lds16(Vt + (size_t)h * DKH * S_LEN + (size_t)row * S_LEN + kv0 + csrc * 8,
                        Vs + (i * 32 + wv * 8) * 64);
        }
        __syncthreads();

        // QK^T : sc[n] holds rows (g*4+r), cols n*16+hl of the 16x64 score tile
        f32x4 sc[4] = {};
        #pragma unroll
        for (int s = 0; s < 2; ++s) {
            #pragma unroll
            for (int n = 0; n < 4; ++n) {
                int row = n * 16 + hl;
                int ch = (s * 4 + g) ^ (row & 7);
                bf16x8 kf = *(const bf16x8*)(Ks + row * 64 + ch * 8);
                sc[n] = __builtin_amdgcn_mfma_f32_16x16x32_bf16(aq[s], kf, sc[n], 0, 0, 0);
            }
        }

        unsigned long long mw[4];
        #pragma unroll
        for (int r = 0; r < 4; ++r) mw[r] = mp[(size_t)(qr + g * 4 + r) * 64 + kt];

        float p[4][4];
        float mx[4];
        #pragma unroll
        for (int r = 0; r < 4; ++r) mx[r] = -3.0e38f;
        #pragma unroll
        for (int n = 0; n < 4; ++n)
            #pragma unroll
            for (int r = 0; r < 4; ++r) {
                float vv = sc[n][r] * 0.125f;
                vv = ((mw[r] >> (n * 16 + hl)) & 1ull) ? vv : -1e9f;
                p[n][r] = vv;
                mx[r] = fmaxf(mx[r], vv);
            }
        #pragma unroll
        for (int off = 8; off >= 1; off >>= 1)
            #pragma unroll
            for (int r = 0; r < 4; ++r)
                mx[r] = fmaxf(mx[r], __shfl_xor(mx[r], off, 16));

        float sf[4], rs[4];
        #pragma unroll
        for (int r = 0; r < 4; ++r) {
            float mn = fmaxf(mrun[r], mx[r]);
            sf[r] = __expf(mrun[r] - mn);
            mrun[r] = mn;
            rs[r] = 0.f;
        }
        #pragma unroll
        for (int n = 0; n < 4; ++n)
            #pragma unroll
            for (int r = 0; r < 4; ++r) {
                float e = __expf(p[n][r] - mrun[r]);
                p[n][r] = e;
                rs[r] += e;
            }
        #pragma unroll
        for (int off = 8; off >= 1; off >>= 1)
            #pragma unroll
            for (int r = 0; r < 4; ++r)
                rs[r] += __shfl_xor(rs[r], off, 16);
        #pragma unroll
        for (int r = 0; r < 4; ++r) drun[r] = drun[r] * sf[r] + rs[r];
        #pragma unroll
        for (int nd = 0; nd < 4; ++nd)
            #pragma unroll
            for (int r = 0; r < 4; ++r)
                acco[nd][r] *= sf[r];

        // P (D-layout) -> per-wave LDS (A-layout source), bf16, swizzled
        #pragma unroll
        for (int n = 0; n < 4; ++n)
            #pragma unroll
            for (int r = 0; r < 4; ++r) {
                int row = g * 4 + r;
                int ch = (n * 2 + (hl >> 3)) ^ (row & 7);
                Ps[wv][row * 64 + ch * 8 + (l & 7)] = f2bf(p[n][r]);
            }
        asm volatile("s_waitcnt lgkmcnt(0)" ::: "memory");

        // PV
        #pragma unroll
        for (int s = 0; s < 2; ++s) {
            int pch = (s * 4 + g) ^ (hl & 7);
            bf16x8 pa = *(const bf16x8*)(&Ps[wv][hl * 64 + pch * 8]);
            #pragma unroll
            for (int nd = 0; nd < 4; ++nd) {
                int row = nd * 16 + hl;
                int ch = (s * 4 + g) ^ (row & 7);
                bf16x8 vf = *(const bf16x8*)(Vs + row * 64 + ch * 8);
                acco[nd] = __builtin_amdgcn_mfma_f32_16x16x32_bf16(pa, vf, acco[nd], 0, 0, 0);
            }
        }
    }

    #pragma unroll
    for (int nd = 0; nd < 4; ++nd)
        #pragma unroll
        for (int r = 0; r < 4; ++r) {
            float vv = acco[nd][r] / drun[r];
            ctx[(size_t)(qr + g * 4 + r) * DMODEL + h * DKH + nd * 16 + hl] = f2bf(vv);
        }
}

extern "C" void kernel_launch(void* const* d_in, const int* in_sizes, int n_in,
                              void* d_out, int out_size, void* d_ws, size_t ws_size,
                              hipStream_t stream) {
    (void)in_sizes; (void)n_in; (void)out_size; (void)ws_size;
    const float* q  = (const float*)d_in[0];
    const float* k  = (const float*)d_in[1];
    const float* v  = (const float*)d_in[2];
    const float* Wq = (const float*)d_in[3];
    const float* bq = (const float*)d_in[4];
    const float* Wk = (const float*)d_in[5];
    const float* bk = (const float*)d_in[6];
    const float* Wv = (const float*)d_in[7];
    const float* bv = (const float*)d_in[8];
    const float* Wo = (const float*)d_in[9];
    const float* bo = (const float*)d_in[10];
    const int* mask = (const int*)d_in[11];

    char* ws = (char*)d_ws;
    short* qb  = (short*)(ws + 0);
    short* kb  = (short*)(ws + 6291456);
    short* vb  = (short*)(ws + 12582912);
    short* Wqb = (short*)(ws + 18874368);
    short* Wkb = (short*)(ws + 20054016);
    short* Wvb = (short*)(ws + 21233664);
    short* Wob = (short*)(ws + 22413312);
    short* Qh  = (short*)(ws + 23592960);
    short* Kh  = (short*)(ws + 29884416);
    short* Vt  = (short*)(ws + 36175872);
    unsigned long long* mp = (unsigned long long*)(ws + 42467328);
    short* ctx = (short*)(ws + 44564480);
    // total ws use: 50855936 bytes

    const int NQKV8 = S_LEN * DMODEL / 8;
    const int NW8 = DMODEL * DMODEL / 8;
    cvt_bf16<<<512, 256, 0, stream>>>(q, qb, NQKV8);
    cvt_bf16<<<512, 256, 0, stream>>>(k, kb, NQKV8);
    cvt_bf16<<<512, 256, 0, stream>>>(v, vb, NQKV8);
    cvt_bf16<<<288, 256, 0, stream>>>(Wq, Wqb, NW8);
    cvt_bf16<<<288, 256, 0, stream>>>(Wk, Wkb, NW8);
    cvt_bf16<<<288, 256, 0, stream>>>(Wv, Wvb, NW8);
    cvt_bf16<<<288, 256, 0, stream>>>(Wo, Wob, NW8);
    pack_mask_k<<<2048, 256, 0, stream>>>(mask, mp, S_LEN * S_LEN / 64);

    dim3 gg(S_LEN / 128, DMODEL / 128);
    gemm_bt<0><<<gg, 256, 0, stream>>>(qb, Wqb, bq, Qh);
    gemm_bt<0><<<gg, 256, 0, stream>>>(kb, Wkb, bk, Kh);
    gemm_bt<1><<<gg, 256, 0, stream>>>(vb, Wvb, bv, Vt);

    flash_attn<<<dim3(S_LEN / 64, NHEADS), 256, 0, stream>>>(Qh, Kh, Vt, mp, ctx);

    gemm_bt<2><<<gg, 256, 0, stream>>>(ctx, Wob, bo, d_out);
}

// Round 3
// 175.165 us; speedup vs baseline: 1.6647x; 1.6647x over previous
//
#include <hip/hip_runtime.h>

#define S_LEN 4096
#define DMODEL 768
#define NHEADS 12
#define DKH 64
#define SC2F 0.18033688011112042f  // (1/8) * log2(e)

typedef __attribute__((ext_vector_type(8))) short bf16x8;
typedef __attribute__((ext_vector_type(4))) float f32x4;
typedef __attribute__((ext_vector_type(16))) float f32x16;
typedef __attribute__((ext_vector_type(4))) short s16x4;

#define AS1 __attribute__((address_space(1)))
#define AS3 __attribute__((address_space(3)))

__device__ __forceinline__ short f2bf(float f) {
    union { float f; unsigned u; } x; x.f = f;
    unsigned r = x.u + 0x7fffu + ((x.u >> 16) & 1u);
    return (short)(r >> 16);
}

__device__ __forceinline__ void gload_lds16(const void* g, void* l) {
    __builtin_amdgcn_global_load_lds((const AS1 void*)g, (AS3 void*)l, 16, 0, 0);
}

// ---------------- fp32 -> bf16 converts (fused) ----------------
__global__ void cvt_bf16_3(const float* __restrict__ a, const float* __restrict__ b,
                           const float* __restrict__ c, short* __restrict__ da,
                           short* __restrict__ db, short* __restrict__ dc, int n8) {
    const float* s = blockIdx.z == 0 ? a : blockIdx.z == 1 ? b : c;
    short* d = blockIdx.z == 0 ? da : blockIdx.z == 1 ? db : dc;
    int stride = gridDim.x * blockDim.x;
    for (int i = blockIdx.x * blockDim.x + threadIdx.x; i < n8; i += stride) {
        float4 x = ((const float4*)s)[2 * i];
        float4 y = ((const float4*)s)[2 * i + 1];
        bf16x8 o;
        o[0] = f2bf(x.x); o[1] = f2bf(x.y); o[2] = f2bf(x.z); o[3] = f2bf(x.w);
        o[4] = f2bf(y.x); o[5] = f2bf(y.y); o[6] = f2bf(y.z); o[7] = f2bf(y.w);
        ((bf16x8*)d)[i] = o;
    }
}

__global__ void cvt_bf16_4(const float* __restrict__ a, const float* __restrict__ b,
                           const float* __restrict__ c, const float* __restrict__ e,
                           short* __restrict__ dst, int n8) {
    const float* s = blockIdx.z == 0 ? a : blockIdx.z == 1 ? b : blockIdx.z == 2 ? c : e;
    short* d = dst + (size_t)blockIdx.z * (size_t)n8 * 8;
    int stride = gridDim.x * blockDim.x;
    for (int i = blockIdx.x * blockDim.x + threadIdx.x; i < n8; i += stride) {
        float4 x = ((const float4*)s)[2 * i];
        float4 y = ((const float4*)s)[2 * i + 1];
        bf16x8 o;
        o[0] = f2bf(x.x); o[1] = f2bf(x.y); o[2] = f2bf(x.z); o[3] = f2bf(x.w);
        o[4] = f2bf(y.x); o[5] = f2bf(y.y); o[6] = f2bf(y.z); o[7] = f2bf(y.w);
        ((bf16x8*)d)[i] = o;
    }
}

// ---------------- mask int32 [S][S] -> transposed bitmask [S/64 kblk][S row] ----
__global__ void pack_mask_k(const int* __restrict__ mask, unsigned long long* __restrict__ mpT, int nwords) {
    int lane = threadIdx.x & 63;
    int wid = (blockIdx.x * blockDim.x + threadIdx.x) >> 6;
    int nw = (gridDim.x * blockDim.x) >> 6;
    for (int w = wid; w < nwords; w += nw) {
        int m = mask[(size_t)w * 64 + lane];
        unsigned long long b = __ballot(m != 0);
        if (lane == 0) mpT[(size_t)(w & 63) * S_LEN + (w >> 6)] = b;
    }
}

// ---------------- QKV projection GEMMs, fused over z ----------------
// C[M=4096][N=768] = A @ W^T + bias.  z=0: Q -> [h][s][d] bf16, scaled by SC2F
// z=1: K -> [h][s][d] bf16.  z=2: V -> transposed [h][d][s'] bf16, where s' is
// s with bits 2,3 swapped (column permutation within each 16-kv group so PV's
// B-fragment read matches P's native register layout; involution).
__global__ __launch_bounds__(256) void qkv_gemm(
    const short* __restrict__ qA, const short* __restrict__ kA, const short* __restrict__ vA,
    const short* __restrict__ Wqb, const short* __restrict__ Wkb, const short* __restrict__ Wvb,
    const float* __restrict__ bq, const float* __restrict__ bk, const float* __restrict__ bv,
    short* __restrict__ Qh, short* __restrict__ Kh, short* __restrict__ Vt)
{
    const int z = blockIdx.z;
    const short* A = z == 0 ? qA : z == 1 ? kA : vA;
    const short* B = z == 0 ? Wqb : z == 1 ? Wkb : Wvb;
    const float* bias = z == 0 ? bq : z == 1 ? bk : bv;

    __shared__ __align__(16) short As[128 * 64];
    __shared__ __align__(16) short Bs[128 * 64];
    const int tid = threadIdx.x;
    const int wv = tid >> 6, l = tid & 63;
    const int wr = wv >> 1, wc = wv & 1;
    const int g = l >> 4, hl = l & 15;
    const int m0 = blockIdx.x * 128, n0 = blockIdx.y * 128;
    const int Kd = DMODEL;

    f32x4 acc[4][4] = {};

    for (int kt = 0; kt < Kd; kt += 64) {
        __syncthreads();
        #pragma unroll
        for (int i = 0; i < 4; ++i) {
            int row = i * 32 + wv * 8 + (l >> 3);
            int csrc = (l & 7) ^ (row & 7);
            gload_lds16(A + (size_t)(m0 + row) * Kd + kt + csrc * 8, As + (i * 32 + wv * 8) * 64);
        }
        #pragma unroll
        for (int i = 0; i < 4; ++i) {
            int row = i * 32 + wv * 8 + (l >> 3);
            int csrc = (l & 7) ^ (row & 7);
            gload_lds16(B + (size_t)(n0 + row) * Kd + kt + csrc * 8, Bs + (i * 32 + wv * 8) * 64);
        }
        __syncthreads();
        #pragma unroll
        for (int s = 0; s < 2; ++s) {
            bf16x8 af[4], bf[4];
            #pragma unroll
            for (int m = 0; m < 4; ++m) {
                int row = wr * 64 + m * 16 + hl;
                int ch = (s * 4 + g) ^ (row & 7);
                af[m] = *(const bf16x8*)(As + row * 64 + ch * 8);
            }
            #pragma unroll
            for (int n = 0; n < 4; ++n) {
                int row = wc * 64 + n * 16 + hl;
                int ch = (s * 4 + g) ^ (row & 7);
                bf[n] = *(const bf16x8*)(Bs + row * 64 + ch * 8);
            }
            #pragma unroll
            for (int m = 0; m < 4; ++m)
                #pragma unroll
                for (int n = 0; n < 4; ++n)
                    acc[m][n] = __builtin_amdgcn_mfma_f32_16x16x32_bf16(af[m], bf[n], acc[m][n], 0, 0, 0);
        }
    }

    const float scale = (z == 0) ? SC2F : 1.0f;
    #pragma unroll
    for (int m = 0; m < 4; ++m) {
        #pragma unroll
        for (int n = 0; n < 4; ++n) {
            int gsb = m0 + wr * 64 + m * 16 + g * 4;
            int go = n0 + wc * 64 + n * 16 + hl;
            float bvv = bias[go];
            int hh = go >> 6, d = go & 63;
            if (z == 2) {
                s16x4 p;
                #pragma unroll
                for (int r = 0; r < 4; ++r) p[r] = f2bf(acc[m][n][r] + bvv);
                // swap bits 2,3 of the kv index (bits 0,1 are within the quad)
                int gsb2 = (gsb & ~12) | ((gsb & 4) << 1) | ((gsb & 8) >> 1);
                *(s16x4*)(Vt + (size_t)hh * DKH * S_LEN + (size_t)d * S_LEN + gsb2) = p;
            } else {
                short* O = z ? Kh : Qh;
                #pragma unroll
                for (int r = 0; r < 4; ++r)
                    O[(size_t)hh * S_LEN * DKH + (size_t)(gsb + r) * DKH + d] = f2bf((acc[m][n][r] + bvv) * scale);
            }
        }
    }
}

// ---------------- output projection (fp32 out + bias) ----------------
__global__ __launch_bounds__(256) void gemm_out(
    const short* __restrict__ A, const short* __restrict__ B,
    const float* __restrict__ bias, float* __restrict__ O)
{
    __shared__ __align__(16) short As[128 * 64];
    __shared__ __align__(16) short Bs[128 * 64];
    const int tid = threadIdx.x;
    const int wv = tid >> 6, l = tid & 63;
    const int wr = wv >> 1, wc = wv & 1;
    const int g = l >> 4, hl = l & 15;
    const int m0 = blockIdx.x * 128, n0 = blockIdx.y * 128;
    const int Kd = DMODEL;

    f32x4 acc[4][4] = {};

    for (int kt = 0; kt < Kd; kt += 64) {
        __syncthreads();
        #pragma unroll
        for (int i = 0; i < 4; ++i) {
            int row = i * 32 + wv * 8 + (l >> 3);
            int csrc = (l & 7) ^ (row & 7);
            gload_lds16(A + (size_t)(m0 + row) * Kd + kt + csrc * 8, As + (i * 32 + wv * 8) * 64);
        }
        #pragma unroll
        for (int i = 0; i < 4; ++i) {
            int row = i * 32 + wv * 8 + (l >> 3);
            int csrc = (l & 7) ^ (row & 7);
            gload_lds16(B + (size_t)(n0 + row) * Kd + kt + csrc * 8, Bs + (i * 32 + wv * 8) * 64);
        }
        __syncthreads();
        #pragma unroll
        for (int s = 0; s < 2; ++s) {
            bf16x8 af[4], bf[4];
            #pragma unroll
            for (int m = 0; m < 4; ++m) {
                int row = wr * 64 + m * 16 + hl;
                int ch = (s * 4 + g) ^ (row & 7);
                af[m] = *(const bf16x8*)(As + row * 64 + ch * 8);
            }
            #pragma unroll
            for (int n = 0; n < 4; ++n) {
                int row = wc * 64 + n * 16 + hl;
                int ch = (s * 4 + g) ^ (row & 7);
                bf[n] = *(const bf16x8*)(Bs + row * 64 + ch * 8);
            }
            #pragma unroll
            for (int m = 0; m < 4; ++m)
                #pragma unroll
                for (int n = 0; n < 4; ++n)
                    acc[m][n] = __builtin_amdgcn_mfma_f32_16x16x32_bf16(af[m], bf[n], acc[m][n], 0, 0, 0);
        }
    }

    #pragma unroll
    for (int m = 0; m < 4; ++m) {
        #pragma unroll
        for (int n = 0; n < 4; ++n) {
            int gsb = m0 + wr * 64 + m * 16 + g * 4;
            int go = n0 + wc * 64 + n * 16 + hl;
            float bvv = bias[go];
            #pragma unroll
            for (int r = 0; r < 4; ++r)
                O[(size_t)(gsb + r) * DMODEL + go] = acc[m][n][r] + bvv;
        }
    }
}

// ---------------- flash attention v3: swapped QK^T, 32x32x16, no-max softmax ----
// 4 waves: wq = wv>>1 (q sub-tile of 32 rows), sp = wv&1 (kv split half).
// Qh/Kh: [12][4096][64] bf16 (Qh pre-scaled by SC2F); Vt: [12][64][4096] bf16
// with kv bits 2,3 swapped; mpT: [64 kblk][4096 row] u64; ctx: [4096][768] bf16.
// P stays in registers: pa slot (hi,e) holds P[q][kv = 16ks + 8(e>>2) + 4hi + (e&3)],
// which is exactly what the bit-swapped V tile delivers per b128 chunk. No lane swap.
__global__ __launch_bounds__(256) void flash_attn2(
    const short* __restrict__ Qh, const short* __restrict__ Kh,
    const short* __restrict__ Vt, const unsigned long long* __restrict__ mpT,
    short* __restrict__ ctx)
{
    __shared__ __align__(16) char pool[33024];

    const int tid = threadIdx.x;
    const int wv = tid >> 6, l = tid & 63;
    const int wq = wv >> 1, sp = wv & 1;
    const int hi = l >> 5, q = l & 31;

    // XCD-chunked remap: 768 blocks -> 96 consecutive work items per XCD (1.5 heads)
    int fid = blockIdx.x + (blockIdx.y << 6);
    int g = (fid & 7) * 96 + (fid >> 3);
    const int h = g >> 6;
    const int q0 = (g & 63) * 64;

    const size_t qkbase = (size_t)h * S_LEN * DKH;
    const size_t vbase = (size_t)h * DKH * S_LEN;

    // Q fragments (B-operand): col=q=lane&31, k = hi*8+j, slice s covers d = s*16..+16
    bf16x8 aq[4];
    #pragma unroll
    for (int s = 0; s < 4; ++s)
        aq[s] = *(const bf16x8*)(Qh + qkbase + (size_t)(q0 + wq * 32 + q) * DKH + s * 16 + hi * 8);

    f32x16 acc[2] = {};
    float dacc[4] = {0.f, 0.f, 0.f, 0.f};

    short* Kl = (short*)(pool + sp * 8192);
    short* Vl = (short*)(pool + 16384 + sp * 8192);

    for (int i = 0; i < 32; ++i) {
        const int kt = i * 2 + sp;
        const int kv0 = kt * 64;
        __syncthreads();
        // stage K (64 kv-rows x 64 d) and V^T (64 d-rows x 64 kv') tiles, row-pair
        // swizzled layout: [32 rp][16 chunks of 16B], chunk' = ((row&1)*8+c) ^ (rp&15)
        #pragma unroll
        for (int j = 0; j < 4; ++j) {
            int rp = (wq * 4 + j) * 4 + (l >> 4);
            int x = (l & 15) ^ (rp & 15);
            int row = rp * 2 + (x >> 3);
            int c = x & 7;
            gload_lds16(Kh + qkbase + (size_t)(kv0 + row) * DKH + c * 8, Kl + (wq * 4 + j) * 512);
            gload_lds16(Vt + vbase + (size_t)row * S_LEN + kv0 + c * 8, Vl + (wq * 4 + j) * 512);
        }
        unsigned long long w = mpT[(size_t)kt * S_LEN + (q0 + wq * 32 + q)];
        __syncthreads();

        unsigned long long w2 = w >> (hi * 4);
        unsigned mlo = (unsigned)w2, mhi2 = (unsigned)(w2 >> 32);

        #pragma unroll
        for (int t = 0; t < 2; ++t) {
            const unsigned msk = t ? mhi2 : mlo;
            // QK^T swapped: st = K_tile(t) * Q  ->  rows=kv, cols=q
            f32x16 st = {};
            #pragma unroll
            for (int s = 0; s < 4; ++s) {
                int rowb = t * 32 + q;
                int rp = rowb >> 1;
                int ch = (((rowb & 1) << 3) + (s * 2 + hi)) ^ (rp & 15);
                bf16x8 kf = *(const bf16x8*)(Kl + rp * 128 + ch * 8);
                st = __builtin_amdgcn_mfma_f32_32x32x16_bf16(kf, aq[s], st, 0, 0, 0);
            }
            // no-max softmax: P = exp2(score); masked -> exp2(-120) ~ 7e-37
            float pf[16];
            #pragma unroll
            for (int r = 0; r < 16; ++r) {
                const int cbit = (r & 3) + 8 * (r >> 2);
                float sv = (msk & (1u << cbit)) ? st[r] : -120.0f;
                pf[r] = __builtin_amdgcn_exp2f(sv);
                dacc[r & 3] += pf[r];
            }
            // P -> A-fragments: direct cvt_pk in register order. pa slot (hi,e)
            // holds kv = 16*ks + 8*(e>>2) + 4*hi + (e&3); V tile columns are
            // bit-2/3-swapped so vf chunk (ks*2+hi) has the identical kv order.
            #pragma unroll
            for (int kk = 0; kk < 2; ++kk) {
                const float* pp = pf + kk * 8;
                union { unsigned u[4]; bf16x8 v; } pa;
                asm("v_cvt_pk_bf16_f32 %0, %1, %2" : "=v"(pa.u[0]) : "v"(pp[0]), "v"(pp[1]));
                asm("v_cvt_pk_bf16_f32 %0, %1, %2" : "=v"(pa.u[1]) : "v"(pp[2]), "v"(pp[3]));
                asm("v_cvt_pk_bf16_f32 %0, %1, %2" : "=v"(pa.u[2]) : "v"(pp[4]), "v"(pp[5]));
                asm("v_cvt_pk_bf16_f32 %0, %1, %2" : "=v"(pa.u[3]) : "v"(pp[6]), "v"(pp[7]));
                const int ks = t * 2 + kk;
                #pragma unroll
                for (int dt = 0; dt < 2; ++dt) {
                    int rowb = dt * 32 + q;
                    int rp = rowb >> 1;
                    int ch = (((rowb & 1) << 3) + (ks * 2 + hi)) ^ (rp & 15);
                    bf16x8 vf = *(const bf16x8*)(Vl + rp * 128 + ch * 8);
                    acc[dt] = __builtin_amdgcn_mfma_f32_32x32x16_bf16(pa.v, vf, acc[dt], 0, 0, 0);
                }
            }
        }
    }

    const float dsum = dacc[0] + dacc[1] + dacc[2] + dacc[3];

    // merge split halves through LDS (pure adds: no max tracking)
    __syncthreads();
    float* accb = (float*)pool;                    // [4 wq*2+dt][16 r][64 l] = 16 KB
    float* ddb  = (float*)(pool + 16384);          // [4 wv][64 l]
    float* dinv = (float*)(pool + 16384 + 1024);   // [2 wq][32 q]
    ddb[wv * 64 + l] = dsum;
    if (sp == 1) {
        #pragma unroll
        for (int dt = 0; dt < 2; ++dt)
            #pragma unroll
            for (int r = 0; r < 16; ++r)
                accb[(((wq * 2 + dt) * 16 + r) << 6) + l] = acc[dt][r];
    }
    __syncthreads();
    if (sp == 0) {
        float dq = ddb[(wq * 2) * 64 + q] + ddb[(wq * 2) * 64 + 32 + q]
                 + ddb[(wq * 2 + 1) * 64 + q] + ddb[(wq * 2 + 1) * 64 + 32 + q];
        if (hi == 0) dinv[wq * 32 + q] = 1.0f / dq;
    }
    __syncthreads();
    if (sp == 0) {
        #pragma unroll
        for (int dt = 0; dt < 2; ++dt) {
            #pragma unroll
            for (int r = 0; r < 16; ++r) {
                float o = acc[dt][r] + accb[(((wq * 2 + dt) * 16 + r) << 6) + l];
                int qo = (r & 3) + 8 * (r >> 2) + 4 * hi;
                float inv = dinv[wq * 32 + qo];
                ctx[(size_t)(q0 + wq * 32 + qo) * DMODEL + h * DKH + dt * 32 + q] = f2bf(o * inv);
            }
        }
    }
}

extern "C" void kernel_launch(void* const* d_in, const int* in_sizes, int n_in,
                              void* d_out, int out_size, void* d_ws, size_t ws_size,
                              hipStream_t stream) {
    (void)in_sizes; (void)n_in; (void)out_size; (void)ws_size;
    const float* q  = (const float*)d_in[0];
    const float* k  = (const float*)d_in[1];
    const float* v  = (const float*)d_in[2];
    const float* Wq = (const float*)d_in[3];
    const float* bq = (const float*)d_in[4];
    const float* Wk = (const float*)d_in[5];
    const float* bk = (const float*)d_in[6];
    const float* Wv = (const float*)d_in[7];
    const float* bv = (const float*)d_in[8];
    const float* Wo = (const float*)d_in[9];
    const float* bo = (const float*)d_in[10];
    const int* mask = (const int*)d_in[11];

    char* ws = (char*)d_ws;
    short* qb  = (short*)(ws + 0);
    short* kb  = (short*)(ws + 6291456);
    short* vb  = (short*)(ws + 12582912);
    short* Wqb = (short*)(ws + 18874368);   // Wq/Wk/Wv/Wo contiguous, 1179648 B each
    short* Wkb = (short*)(ws + 20054016);
    short* Wvb = (short*)(ws + 21233664);
    short* Wob = (short*)(ws + 22413312);
    short* Qh  = (short*)(ws + 23592960);
    short* Kh  = (short*)(ws + 29884416);
    short* Vt  = (short*)(ws + 36175872);
    unsigned long long* mpT = (unsigned long long*)(ws + 42467328);
    short* ctx = (short*)(ws + 44564480);
    // total ws use: 50855936 bytes

    const int NQKV8 = S_LEN * DMODEL / 8;
    const int NW8 = DMODEL * DMODEL / 8;
    cvt_bf16_3<<<dim3(512, 1, 3), 256, 0, stream>>>(q, k, v, qb, kb, vb, NQKV8);
    cvt_bf16_4<<<dim3(288, 1, 4), 256, 0, stream>>>(Wq, Wk, Wv, Wo, Wqb, NW8);
    pack_mask_k<<<2048, 256, 0, stream>>>(mask, mpT, S_LEN * S_LEN / 64);

    qkv_gemm<<<dim3(S_LEN / 128, DMODEL / 128, 3), 256, 0, stream>>>(
        qb, kb, vb, Wqb, Wkb, Wvb, bq, bk, bv, Qh, Kh, Vt);

    flash_attn2<<<dim3(64, 12), 256, 0, stream>>>(Qh, Kh, Vt, mpT, ctx);

    gemm_out<<<dim3(S_LEN / 128, DMODEL / 128), 256, 0, stream>>>(ctx, Wob, bo, (float*)d_out);
}

// Round 6
// 164.772 us; speedup vs baseline: 1.7697x; 1.0631x over previous
//
#include <hip/hip_runtime.h>

#define S_LEN 4096
#define DMODEL 768
#define NHEADS 12
#define DKH 64
#define SC2F 0.18033688011112042f  // (1/8) * log2(e)

typedef __attribute__((ext_vector_type(8))) short bf16x8;
typedef __attribute__((ext_vector_type(4))) float f32x4;
typedef __attribute__((ext_vector_type(16))) float f32x16;
typedef __attribute__((ext_vector_type(4))) short s16x4;

#define AS1 __attribute__((address_space(1)))
#define AS3 __attribute__((address_space(3)))

__device__ __forceinline__ short f2bf(float f) {
    union { float f; unsigned u; } x; x.f = f;
    unsigned r = x.u + 0x7fffu + ((x.u >> 16) & 1u);
    return (short)(r >> 16);
}

__device__ __forceinline__ void gload_lds16(const void* g, void* l) {
    __builtin_amdgcn_global_load_lds((const AS1 void*)g, (AS3 void*)l, 16, 0, 0);
}

// ---------------- fp32 -> bf16 converts (fused) ----------------
__global__ void cvt_bf16_3(const float* __restrict__ a, const float* __restrict__ b,
                           const float* __restrict__ c, short* __restrict__ da,
                           short* __restrict__ db, short* __restrict__ dc, int n8) {
    const float* s = blockIdx.z == 0 ? a : blockIdx.z == 1 ? b : c;
    short* d = blockIdx.z == 0 ? da : blockIdx.z == 1 ? db : dc;
    int stride = gridDim.x * blockDim.x;
    for (int i = blockIdx.x * blockDim.x + threadIdx.x; i < n8; i += stride) {
        float4 x = ((const float4*)s)[2 * i];
        float4 y = ((const float4*)s)[2 * i + 1];
        bf16x8 o;
        o[0] = f2bf(x.x); o[1] = f2bf(x.y); o[2] = f2bf(x.z); o[3] = f2bf(x.w);
        o[4] = f2bf(y.x); o[5] = f2bf(y.y); o[6] = f2bf(y.z); o[7] = f2bf(y.w);
        ((bf16x8*)d)[i] = o;
    }
}

__global__ void cvt_bf16_4(const float* __restrict__ a, const float* __restrict__ b,
                           const float* __restrict__ c, const float* __restrict__ e,
                           short* __restrict__ dst, int n8) {
    const float* s = blockIdx.z == 0 ? a : blockIdx.z == 1 ? b : blockIdx.z == 2 ? c : e;
    short* d = dst + (size_t)blockIdx.z * (size_t)n8 * 8;
    int stride = gridDim.x * blockDim.x;
    for (int i = blockIdx.x * blockDim.x + threadIdx.x; i < n8; i += stride) {
        float4 x = ((const float4*)s)[2 * i];
        float4 y = ((const float4*)s)[2 * i + 1];
        bf16x8 o;
        o[0] = f2bf(x.x); o[1] = f2bf(x.y); o[2] = f2bf(x.z); o[3] = f2bf(x.w);
        o[4] = f2bf(y.x); o[5] = f2bf(y.y); o[6] = f2bf(y.z); o[7] = f2bf(y.w);
        ((bf16x8*)d)[i] = o;
    }
}

// ---------------- mask int32 [S][S] -> transposed bitmask [S/64 kblk][S row] ----
__global__ void pack_mask_k(const int* __restrict__ mask, unsigned long long* __restrict__ mpT, int nwords) {
    int lane = threadIdx.x & 63;
    int wid = (blockIdx.x * blockDim.x + threadIdx.x) >> 6;
    int nw = (gridDim.x * blockDim.x) >> 6;
    for (int w = wid; w < nwords; w += nw) {
        int m = mask[(size_t)w * 64 + lane];
        unsigned long long b = __ballot(m != 0);
        if (lane == 0) mpT[(size_t)(w & 63) * S_LEN + (w >> 6)] = b;
    }
}

// ---------------- QKV projection GEMMs, fused over z ----------------
// C[M=4096][N=768] = A @ W^T + bias.  z=0: Q -> [h][s][d] bf16, scaled by SC2F
// z=1: K -> [h][s][d] bf16.  z=2: V -> transposed [h][d][s'] bf16, where s' is
// s with bits 2,3 swapped (column permutation within each 16-kv group so PV's
// B-fragment read matches P's native register layout; involution).
__global__ __launch_bounds__(256) void qkv_gemm(
    const short* __restrict__ qA, const short* __restrict__ kA, const short* __restrict__ vA,
    const short* __restrict__ Wqb, const short* __restrict__ Wkb, const short* __restrict__ Wvb,
    const float* __restrict__ bq, const float* __restrict__ bk, const float* __restrict__ bv,
    short* __restrict__ Qh, short* __restrict__ Kh, short* __restrict__ Vt)
{
    const int z = blockIdx.z;
    const short* A = z == 0 ? qA : z == 1 ? kA : vA;
    const short* B = z == 0 ? Wqb : z == 1 ? Wkb : Wvb;
    const float* bias = z == 0 ? bq : z == 1 ? bk : bv;

    __shared__ __align__(16) short As[128 * 64];
    __shared__ __align__(16) short Bs[128 * 64];
    const int tid = threadIdx.x;
    const int wv = tid >> 6, l = tid & 63;
    const int wr = wv >> 1, wc = wv & 1;
    const int g = l >> 4, hl = l & 15;
    const int m0 = blockIdx.x * 128, n0 = blockIdx.y * 128;
    const int Kd = DMODEL;

    f32x4 acc[4][4] = {};

    for (int kt = 0; kt < Kd; kt += 64) {
        __syncthreads();
        #pragma unroll
        for (int i = 0; i < 4; ++i) {
            int row = i * 32 + wv * 8 + (l >> 3);
            int csrc = (l & 7) ^ (row & 7);
            gload_lds16(A + (size_t)(m0 + row) * Kd + kt + csrc * 8, As + (i * 32 + wv * 8) * 64);
        }
        #pragma unroll
        for (int i = 0; i < 4; ++i) {
            int row = i * 32 + wv * 8 + (l >> 3);
            int csrc = (l & 7) ^ (row & 7);
            gload_lds16(B + (size_t)(n0 + row) * Kd + kt + csrc * 8, Bs + (i * 32 + wv * 8) * 64);
        }
        __syncthreads();
        #pragma unroll
        for (int s = 0; s < 2; ++s) {
            bf16x8 af[4], bf[4];
            #pragma unroll
            for (int m = 0; m < 4; ++m) {
                int row = wr * 64 + m * 16 + hl;
                int ch = (s * 4 + g) ^ (row & 7);
                af[m] = *(const bf16x8*)(As + row * 64 + ch * 8);
            }
            #pragma unroll
            for (int n = 0; n < 4; ++n) {
                int row = wc * 64 + n * 16 + hl;
                int ch = (s * 4 + g) ^ (row & 7);
                bf[n] = *(const bf16x8*)(Bs + row * 64 + ch * 8);
            }
            #pragma unroll
            for (int m = 0; m < 4; ++m)
                #pragma unroll
                for (int n = 0; n < 4; ++n)
                    acc[m][n] = __builtin_amdgcn_mfma_f32_16x16x32_bf16(af[m], bf[n], acc[m][n], 0, 0, 0);
        }
    }

    const float scale = (z == 0) ? SC2F : 1.0f;
    #pragma unroll
    for (int m = 0; m < 4; ++m) {
        #pragma unroll
        for (int n = 0; n < 4; ++n) {
            int gsb = m0 + wr * 64 + m * 16 + g * 4;
            int go = n0 + wc * 64 + n * 16 + hl;
            float bvv = bias[go];
            int hh = go >> 6, d = go & 63;
            if (z == 2) {
                s16x4 p;
                #pragma unroll
                for (int r = 0; r < 4; ++r) p[r] = f2bf(acc[m][n][r] + bvv);
                // swap bits 2,3 of the kv index (bits 0,1 are within the quad)
                int gsb2 = (gsb & ~12) | ((gsb & 4) << 1) | ((gsb & 8) >> 1);
                *(s16x4*)(Vt + (size_t)hh * DKH * S_LEN + (size_t)d * S_LEN + gsb2) = p;
            } else {
                short* O = z ? Kh : Qh;
                #pragma unroll
                for (int r = 0; r < 4; ++r)
                    O[(size_t)hh * S_LEN * DKH + (size_t)(gsb + r) * DKH + d] = f2bf((acc[m][n][r] + bvv) * scale);
            }
        }
    }
}

// ---------------- output projection (fp32 out + bias) ----------------
__global__ __launch_bounds__(256) void gemm_out(
    const short* __restrict__ A, const short* __restrict__ B,
    const float* __restrict__ bias, float* __restrict__ O)
{
    __shared__ __align__(16) short As[128 * 64];
    __shared__ __align__(16) short Bs[128 * 64];
    const int tid = threadIdx.x;
    const int wv = tid >> 6, l = tid & 63;
    const int wr = wv >> 1, wc = wv & 1;
    const int g = l >> 4, hl = l & 15;
    const int m0 = blockIdx.x * 128, n0 = blockIdx.y * 128;
    const int Kd = DMODEL;

    f32x4 acc[4][4] = {};

    for (int kt = 0; kt < Kd; kt += 64) {
        __syncthreads();
        #pragma unroll
        for (int i = 0; i < 4; ++i) {
            int row = i * 32 + wv * 8 + (l >> 3);
            int csrc = (l & 7) ^ (row & 7);
            gload_lds16(A + (size_t)(m0 + row) * Kd + kt + csrc * 8, As + (i * 32 + wv * 8) * 64);
        }
        #pragma unroll
        for (int i = 0; i < 4; ++i) {
            int row = i * 32 + wv * 8 + (l >> 3);
            int csrc = (l & 7) ^ (row & 7);
            gload_lds16(B + (size_t)(n0 + row) * Kd + kt + csrc * 8, Bs + (i * 32 + wv * 8) * 64);
        }
        __syncthreads();
        #pragma unroll
        for (int s = 0; s < 2; ++s) {
            bf16x8 af[4], bf[4];
            #pragma unroll
            for (int m = 0; m < 4; ++m) {
                int row = wr * 64 + m * 16 + hl;
                int ch = (s * 4 + g) ^ (row & 7);
                af[m] = *(const bf16x8*)(As + row * 64 + ch * 8);
            }
            #pragma unroll
            for (int n = 0; n < 4; ++n) {
                int row = wc * 64 + n * 16 + hl;
                int ch = (s * 4 + g) ^ (row & 7);
                bf[n] = *(const bf16x8*)(Bs + row * 64 + ch * 8);
            }
            #pragma unroll
            for (int m = 0; m < 4; ++m)
                #pragma unroll
                for (int n = 0; n < 4; ++n)
                    acc[m][n] = __builtin_amdgcn_mfma_f32_16x16x32_bf16(af[m], bf[n], acc[m][n], 0, 0, 0);
        }
    }

    #pragma unroll
    for (int m = 0; m < 4; ++m) {
        #pragma unroll
        for (int n = 0; n < 4; ++n) {
            int gsb = m0 + wr * 64 + m * 16 + g * 4;
            int go = n0 + wc * 64 + n * 16 + hl;
            float bvv = bias[go];
            #pragma unroll
            for (int r = 0; r < 4; ++r)
                O[(size_t)(gsb + r) * DMODEL + go] = acc[m][n][r] + bvv;
        }
    }
}

// ---------------- flash attention v6: QBLK=128, 8 waves, v3 sync structure ----
// Per-wave math/layout VERBATIM from the passing v3 kernel. 8 waves =
// 4 wq (32 q-rows each) x 2 sp (kv split halves). Stage of each sp-half's
// 64x64 K and V^T tiles is split across the 4 wq-waves (2 chunks each).
// Same stage -> barrier -> compute -> barrier pattern as v3 (compiler-
// proven drain). Grid 384 blocks, all co-resident (2 blocks/CU), so
// barrier stalls are hidden by the other block's waves. setprio around
// MFMA clusters (T5).
__global__ __launch_bounds__(512) void flash_attn4(
    const short* __restrict__ Qh, const short* __restrict__ Kh,
    const short* __restrict__ Vt, const unsigned long long* __restrict__ mpT,
    short* __restrict__ ctx)
{
    __shared__ __align__(16) char pool[35328];

    const int tid = threadIdx.x;
    const int wv = tid >> 6, l = tid & 63;
    const int wq = wv >> 1, sp = wv & 1;
    const int hi = l >> 5, q = l & 31;

    // XCD-chunked remap: 384 blocks -> 48 consecutive work items per XCD
    int fid = blockIdx.x + (blockIdx.y << 5);
    int g = (fid & 7) * 48 + (fid >> 3);
    const int h = g >> 5;            // 32 q-blocks per head
    const int q0 = (g & 31) * 128;

    const short* Khb = Kh + (size_t)h * S_LEN * DKH;
    const short* Vtb = Vt + (size_t)h * DKH * S_LEN;
    const int qrow = q0 + wq * 32 + q;

    // Q fragments (B-operand): col=q, k = hi*8+j, slice s covers d = s*16..+16
    bf16x8 aq[4];
    #pragma unroll
    for (int s = 0; s < 4; ++s)
        aq[s] = *(const bf16x8*)(Qh + (size_t)h * S_LEN * DKH + (size_t)qrow * DKH + s * 16 + hi * 8);

    f32x16 acc[2] = {};
    float dacc[4] = {0.f, 0.f, 0.f, 0.f};

    short* Kl = (short*)(pool + sp * 8192);           // [0, 16384)
    short* Vl = (short*)(pool + 16384 + sp * 8192);   // [16384, 32768)

    for (int i = 0; i < 32; ++i) {
        const int kt = i * 2 + sp;
        const int kv0 = kt * 64;
        __syncthreads();
        // stage K (64 kv x 64 d) and V^T (64 d x 64 kv') tiles, row-pair
        // swizzled layout: [32 rp][16 chunks of 16B], chunk' = ((row&1)*8+c) ^ (rp&15)
        // 4 wq-waves x 2 chunks each cover rp 0..31.
        #pragma unroll
        for (int j = 0; j < 2; ++j) {
            int rp = (wq * 2 + j) * 4 + (l >> 4);
            int x = (l & 15) ^ (rp & 15);
            int row = rp * 2 + (x >> 3);
            int c = x & 7;
            gload_lds16(Khb + (size_t)(kv0 + row) * DKH + c * 8, Kl + (wq * 2 + j) * 512);
            gload_lds16(Vtb + (size_t)row * S_LEN + kv0 + c * 8, Vl + (wq * 2 + j) * 512);
        }
        unsigned long long w = mpT[(size_t)kt * S_LEN + qrow];
        __syncthreads();

        unsigned long long w2 = w >> (hi * 4);
        unsigned mlo = (unsigned)w2, mhi2 = (unsigned)(w2 >> 32);

        #pragma unroll
        for (int t = 0; t < 2; ++t) {
            const unsigned msk = t ? mhi2 : mlo;
            // QK^T swapped: st = K_tile(t) * Q  ->  rows=kv, cols=q
            f32x16 st = {};
            __builtin_amdgcn_s_setprio(1);
            #pragma unroll
            for (int s = 0; s < 4; ++s) {
                int rowb = t * 32 + q;
                int rp = rowb >> 1;
                int ch = (((rowb & 1) << 3) + (s * 2 + hi)) ^ (rp & 15);
                bf16x8 kf = *(const bf16x8*)(Kl + rp * 128 + ch * 8);
                st = __builtin_amdgcn_mfma_f32_32x32x16_bf16(kf, aq[s], st, 0, 0, 0);
            }
            __builtin_amdgcn_s_setprio(0);
            // no-max softmax: P = exp2(score); masked -> exp2(-120) ~ 7e-37
            float pf[16];
            #pragma unroll
            for (int r = 0; r < 16; ++r) {
                const int cbit = (r & 3) + 8 * (r >> 2);
                float sv = (msk & (1u << cbit)) ? st[r] : -120.0f;
                pf[r] = __builtin_amdgcn_exp2f(sv);
                dacc[r & 3] += pf[r];
            }
            // P -> A-fragments: direct cvt_pk in register order (bit-2/3-swapped V)
            __builtin_amdgcn_s_setprio(1);
            #pragma unroll
            for (int kk = 0; kk < 2; ++kk) {
                const float* pp = pf + kk * 8;
                union { unsigned u[4]; bf16x8 v; } pa;
                asm("v_cvt_pk_bf16_f32 %0, %1, %2" : "=v"(pa.u[0]) : "v"(pp[0]), "v"(pp[1]));
                asm("v_cvt_pk_bf16_f32 %0, %1, %2" : "=v"(pa.u[1]) : "v"(pp[2]), "v"(pp[3]));
                asm("v_cvt_pk_bf16_f32 %0, %1, %2" : "=v"(pa.u[2]) : "v"(pp[4]), "v"(pp[5]));
                asm("v_cvt_pk_bf16_f32 %0, %1, %2" : "=v"(pa.u[3]) : "v"(pp[6]), "v"(pp[7]));
                const int ks = t * 2 + kk;
                #pragma unroll
                for (int dt = 0; dt < 2; ++dt) {
                    int rowb = dt * 32 + q;
                    int rp = rowb >> 1;
                    int ch = (((rowb & 1) << 3) + (ks * 2 + hi)) ^ (rp & 15);
                    bf16x8 vf = *(const bf16x8*)(Vl + rp * 128 + ch * 8);
                    acc[dt] = __builtin_amdgcn_mfma_f32_32x32x16_bf16(pa.v, vf, acc[dt], 0, 0, 0);
                }
            }
            __builtin_amdgcn_s_setprio(0);
        }
    }

    const float dsum = dacc[0] + dacc[1] + dacc[2] + dacc[3];

    // merge split halves through LDS (pure adds: no max tracking); reuses pool
    __syncthreads();
    float* accb = (float*)pool;                    // [4 wq x 2 dt][16 r][64 l] = 32 KB
    float* ddb  = (float*)(pool + 32768);          // [8 wv][64 l] = 2 KB
    float* dinv = (float*)(pool + 34816);          // [4 wq][32 q] = 512 B
    ddb[wv * 64 + l] = dsum;
    if (sp == 1) {
        #pragma unroll
        for (int dt = 0; dt < 2; ++dt)
            #pragma unroll
            for (int r = 0; r < 16; ++r)
                accb[(((wq * 2 + dt) * 16 + r) << 6) + l] = acc[dt][r];
    }
    __syncthreads();
    if (sp == 0) {
        float dq = ddb[(wq * 2) * 64 + q] + ddb[(wq * 2) * 64 + 32 + q]
                 + ddb[(wq * 2 + 1) * 64 + q] + ddb[(wq * 2 + 1) * 64 + 32 + q];
        if (hi == 0) dinv[wq * 32 + q] = 1.0f / dq;
    }
    __syncthreads();
    if (sp == 0) {
        #pragma unroll
        for (int dt = 0; dt < 2; ++dt) {
            #pragma unroll
            for (int r = 0; r < 16; ++r) {
                float o = acc[dt][r] + accb[(((wq * 2 + dt) * 16 + r) << 6) + l];
                int qo = (r & 3) + 8 * (r >> 2) + 4 * hi;
                float inv = dinv[wq * 32 + qo];
                ctx[(size_t)(q0 + wq * 32 + qo) * DMODEL + h * DKH + dt * 32 + q] = f2bf(o * inv);
            }
        }
    }
}

extern "C" void kernel_launch(void* const* d_in, const int* in_sizes, int n_in,
                              void* d_out, int out_size, void* d_ws, size_t ws_size,
                              hipStream_t stream) {
    (void)in_sizes; (void)n_in; (void)out_size; (void)ws_size;
    const float* q  = (const float*)d_in[0];
    const float* k  = (const float*)d_in[1];
    const float* v  = (const float*)d_in[2];
    const float* Wq = (const float*)d_in[3];
    const float* bq = (const float*)d_in[4];
    const float* Wk = (const float*)d_in[5];
    const float* bk = (const float*)d_in[6];
    const float* Wv = (const float*)d_in[7];
    const float* bv = (const float*)d_in[8];
    const float* Wo = (const float*)d_in[9];
    const float* bo = (const float*)d_in[10];
    const int* mask = (const int*)d_in[11];

    char* ws = (char*)d_ws;
    short* qb  = (short*)(ws + 0);
    short* kb  = (short*)(ws + 6291456);
    short* vb  = (short*)(ws + 12582912);
    short* Wqb = (short*)(ws + 18874368);   // Wq/Wk/Wv/Wo contiguous, 1179648 B each
    short* Wkb = (short*)(ws + 20054016);
    short* Wvb = (short*)(ws + 21233664);
    short* Wob = (short*)(ws + 22413312);
    short* Qh  = (short*)(ws + 23592960);
    short* Kh  = (short*)(ws + 29884416);
    short* Vt  = (short*)(ws + 36175872);
    unsigned long long* mpT = (unsigned long long*)(ws + 42467328);
    short* ctx = (short*)(ws + 44564480);
    // total ws use: 50855936 bytes

    const int NQKV8 = S_LEN * DMODEL / 8;
    const int NW8 = DMODEL * DMODEL / 8;
    cvt_bf16_3<<<dim3(512, 1, 3), 256, 0, stream>>>(q, k, v, qb, kb, vb, NQKV8);
    cvt_bf16_4<<<dim3(288, 1, 4), 256, 0, stream>>>(Wq, Wk, Wv, Wo, Wqb, NW8);
    pack_mask_k<<<2048, 256, 0, stream>>>(mask, mpT, S_LEN * S_LEN / 64);

    qkv_gemm<<<dim3(S_LEN / 128, DMODEL / 128, 3), 256, 0, stream>>>(
        qb, kb, vb, Wqb, Wkb, Wvb, bq, bk, bv, Qh, Kh, Vt);

    flash_attn4<<<dim3(32, 12), 512, 0, stream>>>(Qh, Kh, Vt, mpT, ctx);

    gemm_out<<<dim3(S_LEN / 128, DMODEL / 128), 256, 0, stream>>>(ctx, Wob, bo, (float*)d_out);
}